// Round 8
// baseline (352.181 us; speedup 1.0000x reference)
//
#include <hip/hip_runtime.h>
#include <hip/hip_bf16.h>

#define NB    16384   // batch
#define NR    2048    // memory rows
#define NC    128     // memory cols (= key dim)
#define KCTRL 1024    // controller dim
#define EPSF  1e-16f
#define NROW  8       // batch rows per block
#define ESTR  2056    // E_s row stride (bf16)
#define XSTR  1032    // x-stage row stride (bf16), overlays E_s

typedef __attribute__((ext_vector_type(8))) short bf16x8;
typedef __attribute__((ext_vector_type(4))) float f32x4;

__device__ __forceinline__ float softplus_f(float x) {
    return fmaxf(x, 0.f) + log1pf(__expf(-fabsf(x)));
}
__device__ __forceinline__ unsigned short f2bf(float f) {
    __hip_bfloat16 h = __float2bfloat16(f);
    return *(unsigned short*)&h;
}
__device__ __forceinline__ float bf2f(unsigned short u) {
    __hip_bfloat16 h;
    *(unsigned short*)&h = u;
    return __bfloat162float(h);
}

// Fragment-order swizzle: element (row n, col k), tiled 16 rows x 32 cols, so
// one wave's 16x32 fragment is 64 lanes x 8 bf16 contiguous (1 KB).
__device__ __forceinline__ size_t swz(int n, int k, int nch) {
    return ((size_t)((n >> 4) * nch + (k >> 5)) * 64 + ((k >> 3) & 3) * 16 + (n & 15)) * 8 + (k & 7);
}

// ---------------- P: merged prep (blocks 0..2047: M; 2048..3071: W) ----------
__global__ __launch_bounds__(64) void prep_all(const float* __restrict__ M,
                                               unsigned short* __restrict__ Mb_sw,
                                               unsigned short* __restrict__ Mt_sw,
                                               float* __restrict__ imn,
                                               const float* __restrict__ W,
                                               unsigned short* __restrict__ Wt_sw) {
    const int bid = blockIdx.x;
    const int l = threadIdx.x;
    if (bid < NR) {
        const int i = bid;
        const float v0 = M[(size_t)i * NC + l];
        const float v1 = M[(size_t)i * NC + 64 + l];
        Mb_sw[swz(i, l, 4)]      = f2bf(v0);
        Mb_sw[swz(i, 64 + l, 4)] = f2bf(v1);
        Mt_sw[swz(l, i, 64)]      = f2bf(v0);
        Mt_sw[swz(64 + l, i, 64)] = f2bf(v1);
        float s = v0 * v0 + v1 * v1;
        #pragma unroll
        for (int m = 1; m < 64; m <<= 1) s += __shfl_xor(s, m);
        if (l == 0) imn[i] = 1.f / sqrtf(s);
    } else {
        const int k = bid - NR;   // 0..1023
        Wt_sw[swz(l, k, 32)]      = f2bf(W[(size_t)k * 134 + l]);
        Wt_sw[swz(64 + l, k, 32)] = f2bf(W[(size_t)k * 134 + 64 + l]);
        if (l < 6) {
            Wt_sw[swz(128 + l, k, 32)] = f2bf(W[(size_t)k * 134 + 128 + l]);
        }
    }
}

// ---------------- Fused: fc + head, 256 threads / 8 batch rows --------------
// ~36 KB LDS -> 4 blocks/CU (vs 2): staggered barrier groups hide each
// other's drains. MFMA tiles are half-empty in M (rows 8..15 garbage,
// masked with quad<2 at every epilogue; l16&7 keeps LDS reads in-bounds).
__global__ __launch_bounds__(256, 4) void fused_ntm(const float* __restrict__ x,
                                                    const unsigned short* __restrict__ Wt_sw,
                                                    const float* __restrict__ bfc,
                                                    const unsigned short* __restrict__ Mb_sw,
                                                    const unsigned short* __restrict__ Mt_sw,
                                                    const float* __restrict__ imn,
                                                    const float* __restrict__ wprev,
                                                    float* __restrict__ out) {
    __shared__ __align__(16) unsigned short E_s[NROW][ESTR];   // 32896 B (x_s overlay)
    __shared__ __align__(16) unsigned short k_s[NROW][136];    // 2176 B
    __shared__ float h6s[NROW][6];
    __shared__ float ksum[NROW];
    __shared__ float scal_s[NROW][6];    // {beta/kn, g, s0, s1, s2, gamma}
    __shared__ float wred[NROW][4];
    __shared__ float fa_s[NROW], fc_s[NROW], invZ_s[NROW];

    unsigned short (*x_s)[XSTR] = (unsigned short(*)[XSTR])E_s;

    const int tid  = threadIdx.x;
    const int w    = tid >> 6;         // 4 waves
    const int lane = tid & 63;
    const int quad = lane >> 4;
    const int l16  = lane & 15;
    const int l8   = l16 & 7;          // in-bounds row index for 8-row buffers
    const int b0   = blockIdx.x * NROW;

    if (tid < NROW) ksum[tid] = 0.f;

    // ---- stage A: x (8x1024 f32) -> LDS bf16, coalesced ----
    #pragma unroll
    for (int p = 0; p < 8; p++) {
        const int idx = p * 256 + tid;          // float4 index, 2048 total
        const int row = idx >> 8;
        const int c4  = idx & 255;
        const float4 v = *(const float4*)(x + (size_t)(b0 + row) * KCTRL + c4 * 4);
        unsigned short* d = &x_s[row][c4 * 4];
        d[0] = f2bf(v.x); d[1] = f2bf(v.y); d[2] = f2bf(v.z); d[3] = f2bf(v.w);
    }
    __syncthreads();

    // ---- stage B: h = x@W + b. Wave w -> col tiles {w, w+4}; wave 3 + tile 8.
    {
        f32x4 acc0 = {0.f, 0.f, 0.f, 0.f};
        f32x4 acc1 = {0.f, 0.f, 0.f, 0.f};
        f32x4 accH = {0.f, 0.f, 0.f, 0.f};
        const unsigned short* p0 = Wt_sw + (size_t)w * 16384 + lane * 8;
        const unsigned short* p1 = Wt_sw + (size_t)(w + 4) * 16384 + lane * 8;
        const unsigned short* p2 = Wt_sw + (size_t)8 * 16384 + lane * 8;
        #pragma unroll 4
        for (int i = 0; i < 32; i++) {
            const bf16x8 a = *(const bf16x8*)&x_s[l8][i * 32 + quad * 8];
            acc0 = __builtin_amdgcn_mfma_f32_16x16x32_bf16(a, *(const bf16x8*)(p0 + (size_t)i * 512), acc0, 0, 0, 0);
            acc1 = __builtin_amdgcn_mfma_f32_16x16x32_bf16(a, *(const bf16x8*)(p1 + (size_t)i * 512), acc1, 0, 0, 0);
            if (w == 3) {
                accH = __builtin_amdgcn_mfma_f32_16x16x32_bf16(a, *(const bf16x8*)(p2 + (size_t)i * 512), accH, 0, 0, 0);
            }
        }
        if (quad < 2) {
            const float bb0 = bfc[w * 16 + l16];
            const float bb1 = bfc[(w + 4) * 16 + l16];
            float part[4];
            #pragma unroll
            for (int reg = 0; reg < 4; reg++) {
                const int m = quad * 4 + reg;     // 0..7
                const float v0 = acc0[reg] + bb0;
                const float v1 = acc1[reg] + bb1;
                k_s[m][w * 16 + l16]       = f2bf(v0);
                k_s[m][(w + 4) * 16 + l16] = f2bf(v1);
                part[reg] = v0 * v0 + v1 * v1;
            }
            #pragma unroll
            for (int s = 1; s < 16; s <<= 1) {
                #pragma unroll
                for (int reg = 0; reg < 4; reg++) part[reg] += __shfl_xor(part[reg], s);
            }
            if (l16 == 0) {
                #pragma unroll
                for (int reg = 0; reg < 4; reg++) atomicAdd(&ksum[quad * 4 + reg], part[reg]);
            }
            if (w == 3 && l16 < 6) {
                const float bh = bfc[128 + l16];
                #pragma unroll
                for (int reg = 0; reg < 4; reg++) h6s[quad * 4 + reg][l16] = accH[reg] + bh;
            }
        }
    }
    __syncthreads();

    if (tid < NROW) {
        const float kn = sqrtf(ksum[tid]);
        const float* h = h6s[tid];
        const float beta = softplus_f(h[0]);
        const float g = 1.f / (1.f + __expf(-h[1]));
        const float m3 = fmaxf(h[2], fmaxf(h[3], h[4]));
        const float e0 = __expf(h[2] - m3), e1 = __expf(h[3] - m3), e2 = __expf(h[4] - m3);
        const float inv = 1.f / (e0 + e1 + e2);
        scal_s[tid][0] = beta / kn;
        scal_s[tid][1] = g;
        scal_s[tid][2] = e0 * inv;
        scal_s[tid][3] = e1 * inv;
        scal_s[tid][4] = e2 * inv;
        scal_s[tid][5] = 1.f + softplus_f(h[5]);
    }
    __syncthreads();

    // ---- phase 1: E = exp((beta/kn)*(1/mn)*(k . M_i)) ----
    {
        float cbs[4];
        #pragma unroll
        for (int reg = 0; reg < 4; reg++) cbs[reg] = scal_s[(quad & 1) * 4 + reg][0];

        const bf16x8 af0 = *(const bf16x8*)&k_s[l8][quad * 8];
        const bf16x8 af1 = *(const bf16x8*)&k_s[l8][32 + quad * 8];
        const bf16x8 af2 = *(const bf16x8*)&k_s[l8][64 + quad * 8];
        const bf16x8 af3 = *(const bf16x8*)&k_s[l8][96 + quad * 8];

        float Sp[4] = {0.f, 0.f, 0.f, 0.f};
        #pragma unroll 4
        for (int t = 0; t < 32; t++) {
            const int nt = w * 32 + t;
            const unsigned short* bp = Mb_sw + (size_t)nt * 2048 + lane * 8;
            f32x4 aA = {0.f, 0.f, 0.f, 0.f};
            f32x4 aB = {0.f, 0.f, 0.f, 0.f};
            aA = __builtin_amdgcn_mfma_f32_16x16x32_bf16(af0, *(const bf16x8*)(bp), aA, 0, 0, 0);
            aB = __builtin_amdgcn_mfma_f32_16x16x32_bf16(af2, *(const bf16x8*)(bp + 1024), aB, 0, 0, 0);
            aA = __builtin_amdgcn_mfma_f32_16x16x32_bf16(af1, *(const bf16x8*)(bp + 512), aA, 0, 0, 0);
            aB = __builtin_amdgcn_mfma_f32_16x16x32_bf16(af3, *(const bf16x8*)(bp + 1536), aB, 0, 0, 0);
            if (quad < 2) {
                const int n0 = nt * 16;
                const float im = imn[n0 + l16];
                #pragma unroll
                for (int reg = 0; reg < 4; reg++) {
                    const float e = __expf((aA[reg] + aB[reg]) * cbs[reg] * im);
                    E_s[quad * 4 + reg][n0 + l16] = f2bf(e);
                    Sp[reg] += e;
                }
            }
        }
        if (quad < 2) {
            #pragma unroll
            for (int s = 1; s < 16; s <<= 1) {
                #pragma unroll
                for (int reg = 0; reg < 4; reg++) Sp[reg] += __shfl_xor(Sp[reg], s);
            }
            if (l16 == 0) {
                #pragma unroll
                for (int reg = 0; reg < 4; reg++) wred[quad * 4 + reg][w] = Sp[reg];
            }
        }
    }
    __syncthreads();
    if (tid < NROW) {
        const float S = wred[tid][0] + wred[tid][1] + wred[tid][2] + wred[tid][3];
        const float g = scal_s[tid][1];
        fa_s[tid] = g / S;
        fc_s[tid] = 1.f - g;
    }
    __syncthreads();

    // ---- phase 1.5: parallel shift+pow, in place, software-pipelined ----
    // Row r owned by a 32-lane half-wave; lane g owns chunks (g+32j)*8.
    // Prefetched chunks (g+32(j+1)) / edge (g+32(j+1))*8-1 are never written
    // during iter j for g>0; the g==0 left edge and g==31/j==7 right wrap go
    // through carry/E0sav registers, so early (stale) raw reads are discarded.
    {
        const int row  = tid >> 5;           // 0..7
        const int g    = tid & 31;
        const int base = tid & 32;           // wave-local half base
        const float s0 = scal_s[row][2], s1 = scal_s[row][3], s2 = scal_s[row][4];
        const float gmm = scal_s[row][5];
        const float fa = fa_s[row], fcm = fc_s[row];
        const float* wp = wprev + (size_t)(b0 + row) * NR;

        int c0 = g * 8;
        bf16x8 E8c = *(const bf16x8*)&E_s[row][c0];
        float eLc  = bf2f(E_s[row][(c0 + NR - 1) & (NR - 1)]);
        float eRc  = bf2f(E_s[row][c0 + 8]);
        float4 wac = *(const float4*)(wp + c0);
        float4 wbc = *(const float4*)(wp + c0 + 4);
        float wpLc = wp[(c0 + NR - 1) & (NR - 1)];
        float wpRc = wp[c0 + 8];

        float Zp = 0.f, carry = 0.f, E0sav = 0.f;
        #pragma unroll
        for (int j = 0; j < 8; j++) {
            bf16x8 E8n; float eLn = 0.f, eRn = 0.f, wpLn = 0.f, wpRn = 0.f;
            float4 wan, wbn;
            if (j < 7) {
                const int c1 = c0 + 256;
                E8n  = *(const bf16x8*)&E_s[row][c1];
                eLn  = bf2f(E_s[row][c1 - 1]);
                eRn  = bf2f(E_s[row][(c1 + 8) & (NR - 1)]);
                wan  = *(const float4*)(wp + c1);
                wbn  = *(const float4*)(wp + c1 + 4);
                wpLn = wp[c1 - 1];
                wpRn = wp[(c1 + 8) & (NR - 1)];
            }
            float ef[8];
            #pragma unroll
            for (int i = 0; i < 8; i++) ef[i] = bf2f((unsigned short)E8c[i]);
            if (j == 0) E0sav = __shfl(ef[0], base);
            const float eL = (g == 0 && j > 0) ? carry : eLc;
            const float eR = (g == 31 && j == 7) ? E0sav : eRc;
            carry = __shfl(ef[7], base + 31);

            float wg[10];
            wg[0] = fmaf(fa, eL,    fcm * wpLc);
            wg[1] = fmaf(fa, ef[0], fcm * wac.x);
            wg[2] = fmaf(fa, ef[1], fcm * wac.y);
            wg[3] = fmaf(fa, ef[2], fcm * wac.z);
            wg[4] = fmaf(fa, ef[3], fcm * wac.w);
            wg[5] = fmaf(fa, ef[4], fcm * wbc.x);
            wg[6] = fmaf(fa, ef[5], fcm * wbc.y);
            wg[7] = fmaf(fa, ef[6], fcm * wbc.z);
            wg[8] = fmaf(fa, ef[7], fcm * wbc.w);
            wg[9] = fmaf(fa, eR,    fcm * wpRc);

            bf16x8 out8;
            #pragma unroll
            for (int i = 0; i < 8; i++) {
                const float wt = fmaf(s0, wg[i], fmaf(s1, wg[i + 1], s2 * wg[i + 2])) + EPSF;
                const float pw = __expf(gmm * __logf(wt));
                Zp += pw;
                out8[i] = (short)f2bf(pw);
            }
            *(bf16x8*)&E_s[row][c0] = out8;

            c0 += 256;
            E8c = E8n; eLc = eLn; eRc = eRn;
            wac = wan; wbc = wbn; wpLc = wpLn; wpRc = wpRn;
        }
        #pragma unroll
        for (int s = 1; s < 32; s <<= 1) Zp += __shfl_xor(Zp, s);
        if (g == 0) invZ_s[row] = 1.f / Zp;
    }
    __syncthreads();

    // ---- phase 2: r = (w_pow @ M) * invZ. Wave w -> col tiles {w, w+4} ----
    #pragma unroll
    for (int cpass = 0; cpass < 2; cpass++) {
        const int c = w + cpass * 4;
        f32x4 acc0 = {0.f, 0.f, 0.f, 0.f};
        f32x4 acc1 = {0.f, 0.f, 0.f, 0.f};
        f32x4 acc2 = {0.f, 0.f, 0.f, 0.f};
        f32x4 acc3 = {0.f, 0.f, 0.f, 0.f};
        const unsigned short* bp = Mt_sw + (size_t)c * 32768 + lane * 8;
        for (int k0 = 0; k0 < NR; k0 += 128) {
            const int C = k0 >> 5;
            const bf16x8 a0 = *(const bf16x8*)&E_s[l8][k0 + quad * 8];
            const bf16x8 a1 = *(const bf16x8*)&E_s[l8][k0 + 32 + quad * 8];
            const bf16x8 a2 = *(const bf16x8*)&E_s[l8][k0 + 64 + quad * 8];
            const bf16x8 a3 = *(const bf16x8*)&E_s[l8][k0 + 96 + quad * 8];
            const bf16x8 b0v = *(const bf16x8*)(bp + (size_t)C * 512);
            const bf16x8 b1v = *(const bf16x8*)(bp + (size_t)(C + 1) * 512);
            const bf16x8 b2v = *(const bf16x8*)(bp + (size_t)(C + 2) * 512);
            const bf16x8 b3v = *(const bf16x8*)(bp + (size_t)(C + 3) * 512);
            acc0 = __builtin_amdgcn_mfma_f32_16x16x32_bf16(a0, b0v, acc0, 0, 0, 0);
            acc1 = __builtin_amdgcn_mfma_f32_16x16x32_bf16(a1, b1v, acc1, 0, 0, 0);
            acc2 = __builtin_amdgcn_mfma_f32_16x16x32_bf16(a2, b2v, acc2, 0, 0, 0);
            acc3 = __builtin_amdgcn_mfma_f32_16x16x32_bf16(a3, b3v, acc3, 0, 0, 0);
        }
        if (quad < 2) {
            #pragma unroll
            for (int reg = 0; reg < 4; reg++) {
                const int m = quad * 4 + reg;     // 0..7
                const float v = (acc0[reg] + acc1[reg]) + (acc2[reg] + acc3[reg]);
                out[(size_t)(b0 + m) * NC + c * 16 + l16] = v * invZ_s[m];
            }
        }
    }
}

extern "C" void kernel_launch(void* const* d_in, const int* in_sizes, int n_in,
                              void* d_out, int out_size, void* d_ws, size_t ws_size,
                              hipStream_t stream) {
    const float* x     = (const float*)d_in[0];
    const float* Wfc   = (const float*)d_in[1];
    const float* bfc   = (const float*)d_in[2];
    const float* M     = (const float*)d_in[3];
    const float* wprev = (const float*)d_in[4];
    float* out = (float*)d_out;

    char* ws = (char*)d_ws;
    float*          imn   = (float*)(ws);                      // 8192 B
    unsigned short* Mb_sw = (unsigned short*)(ws + 8192);      // 524288 B
    unsigned short* Mt_sw = (unsigned short*)(ws + 532480);    // 524288 B
    unsigned short* Wt_sw = (unsigned short*)(ws + 1056768);   // 294912 B

    hipLaunchKernelGGL(prep_all, dim3(NR + KCTRL), dim3(64), 0, stream,
                       M, Mb_sw, Mt_sw, imn, Wfc, Wt_sw);
    hipLaunchKernelGGL(fused_ntm, dim3(NB / NROW), dim3(256), 0, stream,
                       x, Wt_sw, bfc, Mb_sw, Mt_sw, imn, wprev, out);
}

// Round 9
// 291.558 us; speedup vs baseline: 1.2079x; 1.2079x over previous
//
#include <hip/hip_runtime.h>
#include <hip/hip_bf16.h>

#define NB    16384   // batch
#define NR    2048    // memory rows
#define NC    128     // memory cols (= key dim)
#define KCTRL 1024    // controller dim
#define EPSF  1e-16f
#define ESTR  2056    // E_s row stride (bf16)
#define XSTR  1032    // x-stage row stride (bf16), overlays E_s

typedef __attribute__((ext_vector_type(8))) short bf16x8;
typedef __attribute__((ext_vector_type(4))) float f32x4;

__device__ __forceinline__ float softplus_f(float x) {
    return fmaxf(x, 0.f) + log1pf(__expf(-fabsf(x)));
}
__device__ __forceinline__ unsigned short f2bf(float f) {
    __hip_bfloat16 h = __float2bfloat16(f);
    return *(unsigned short*)&h;
}
__device__ __forceinline__ float bf2f(unsigned short u) {
    __hip_bfloat16 h;
    *(unsigned short*)&h = u;
    return __bfloat162float(h);
}

// Fragment-order swizzle: element (row n, col k), tiled 16 rows x 32 cols, so
// one wave's 16x32 fragment is 64 lanes x 8 bf16 contiguous (1 KB).
__device__ __forceinline__ size_t swz(int n, int k, int nch) {
    return ((size_t)((n >> 4) * nch + (k >> 5)) * 64 + ((k >> 3) & 3) * 16 + (n & 15)) * 8 + (k & 7);
}

// ---------------- P: merged prep (blocks 0..2047: M; 2048..3071: W) ----------
__global__ __launch_bounds__(64) void prep_all(const float* __restrict__ M,
                                               unsigned short* __restrict__ Mb_sw,
                                               unsigned short* __restrict__ Mt_sw,
                                               float* __restrict__ imn,
                                               const float* __restrict__ W,
                                               unsigned short* __restrict__ Wt_sw) {
    const int bid = blockIdx.x;
    const int l = threadIdx.x;
    if (bid < NR) {
        const int i = bid;
        const float v0 = M[(size_t)i * NC + l];
        const float v1 = M[(size_t)i * NC + 64 + l];
        Mb_sw[swz(i, l, 4)]      = f2bf(v0);
        Mb_sw[swz(i, 64 + l, 4)] = f2bf(v1);
        Mt_sw[swz(l, i, 64)]      = f2bf(v0);
        Mt_sw[swz(64 + l, i, 64)] = f2bf(v1);
        float s = v0 * v0 + v1 * v1;
        #pragma unroll
        for (int m = 1; m < 64; m <<= 1) s += __shfl_xor(s, m);
        if (l == 0) imn[i] = 1.f / sqrtf(s);
    } else {
        const int k = bid - NR;   // 0..1023
        Wt_sw[swz(l, k, 32)]      = f2bf(W[(size_t)k * 134 + l]);
        Wt_sw[swz(64 + l, k, 32)] = f2bf(W[(size_t)k * 134 + 64 + l]);
        if (l < 6) {
            Wt_sw[swz(128 + l, k, 32)] = f2bf(W[(size_t)k * 134 + 128 + l]);
        }
    }
}

// ---------------- Fused: fc + head, 512 threads / 16 batch rows --------------
// All three MFMA loops use explicit depth-2 software prefetch of the L2
// B-streams (R5->R6 showed this kernel is load-issue bound; VGPR 60 of 128
// budget was idle headroom).
__global__ __launch_bounds__(512, 4) void fused_ntm(const float* __restrict__ x,
                                                    const unsigned short* __restrict__ Wt_sw,
                                                    const float* __restrict__ bfc,
                                                    const unsigned short* __restrict__ Mb_sw,
                                                    const unsigned short* __restrict__ Mt_sw,
                                                    const float* __restrict__ imn,
                                                    const float* __restrict__ wprev,
                                                    float* __restrict__ out) {
    __shared__ __align__(16) unsigned short E_s[16][ESTR];   // 65792 B (x_s overlay)
    __shared__ __align__(16) unsigned short k_s[16][136];    // 4352 B
    __shared__ float h6s[16][6];
    __shared__ float ksum[16];
    __shared__ float scal_s[16][6];    // {beta/kn, g, s0, s1, s2, gamma}
    __shared__ float wred[16][8];
    __shared__ float fa_s[16], fc_s[16], invZ_s[16];

    unsigned short (*x_s)[XSTR] = (unsigned short(*)[XSTR])E_s;

    const int tid  = threadIdx.x;
    const int w    = tid >> 6;         // 8 waves
    const int lane = tid & 63;
    const int quad = lane >> 4;
    const int l16  = lane & 15;
    const int b0   = blockIdx.x * 16;

    if (tid < 16) ksum[tid] = 0.f;

    // ---- stage A: x (16x1024 f32) -> LDS bf16, coalesced ----
    #pragma unroll
    for (int p = 0; p < 8; p++) {
        const int idx = p * 512 + tid;          // float4 index, 4096 total
        const int row = idx >> 8;
        const int c4  = idx & 255;
        const float4 v = *(const float4*)(x + (size_t)(b0 + row) * KCTRL + c4 * 4);
        unsigned short* d = &x_s[row][c4 * 4];
        d[0] = f2bf(v.x); d[1] = f2bf(v.y); d[2] = f2bf(v.z); d[3] = f2bf(v.w);
    }
    __syncthreads();

    // ---- stage B: h = x@W + b. Wave w -> col tile w; wave 0 also tile 8. ----
    {
        f32x4 accF = {0.f, 0.f, 0.f, 0.f};
        f32x4 accH = {0.f, 0.f, 0.f, 0.f};
        const unsigned short* wbp = Wt_sw + (size_t)w * 16384 + lane * 8;
        const unsigned short* whp = Wt_sw + (size_t)8 * 16384 + lane * 8;
        bf16x8 bc0 = *(const bf16x8*)(wbp);
        bf16x8 bc1 = *(const bf16x8*)(wbp + 512);
        #pragma unroll
        for (int i = 0; i < 32; i += 2) {
            bf16x8 bn0, bn1;
            if (i < 30) {
                bn0 = *(const bf16x8*)(wbp + (size_t)(i + 2) * 512);
                bn1 = *(const bf16x8*)(wbp + (size_t)(i + 3) * 512);
            }
            const bf16x8 a0 = *(const bf16x8*)&x_s[l16][i * 32 + quad * 8];
            const bf16x8 a1 = *(const bf16x8*)&x_s[l16][(i + 1) * 32 + quad * 8];
            accF = __builtin_amdgcn_mfma_f32_16x16x32_bf16(a0, bc0, accF, 0, 0, 0);
            accF = __builtin_amdgcn_mfma_f32_16x16x32_bf16(a1, bc1, accF, 0, 0, 0);
            if (w == 0) {
                const bf16x8 h0 = *(const bf16x8*)(whp + (size_t)i * 512);
                const bf16x8 h1 = *(const bf16x8*)(whp + (size_t)(i + 1) * 512);
                accH = __builtin_amdgcn_mfma_f32_16x16x32_bf16(a0, h0, accH, 0, 0, 0);
                accH = __builtin_amdgcn_mfma_f32_16x16x32_bf16(a1, h1, accH, 0, 0, 0);
            }
            bc0 = bn0; bc1 = bn1;
        }
        __syncthreads();          // x_s reads done (E_s overlay safe later)

        const float bb = bfc[w * 16 + l16];
        float part[4];
        #pragma unroll
        for (int reg = 0; reg < 4; reg++) {
            const int m = quad * 4 + reg;
            const float v = accF[reg] + bb;
            k_s[m][w * 16 + l16] = f2bf(v);
            part[reg] = v * v;
        }
        #pragma unroll
        for (int s = 1; s < 16; s <<= 1) {
            #pragma unroll
            for (int reg = 0; reg < 4; reg++) part[reg] += __shfl_xor(part[reg], s);
        }
        if (l16 == 0) {
            #pragma unroll
            for (int reg = 0; reg < 4; reg++) atomicAdd(&ksum[quad * 4 + reg], part[reg]);
        }
        if (w == 0 && l16 < 6) {
            const float bh = bfc[128 + l16];
            #pragma unroll
            for (int reg = 0; reg < 4; reg++) h6s[quad * 4 + reg][l16] = accH[reg] + bh;
        }
    }
    __syncthreads();

    if (tid < 16) {
        const float kn = sqrtf(ksum[tid]);
        const float* h = h6s[tid];
        const float beta = softplus_f(h[0]);
        const float g = 1.f / (1.f + __expf(-h[1]));
        const float m3 = fmaxf(h[2], fmaxf(h[3], h[4]));
        const float e0 = __expf(h[2] - m3), e1 = __expf(h[3] - m3), e2 = __expf(h[4] - m3);
        const float inv = 1.f / (e0 + e1 + e2);
        scal_s[tid][0] = beta / kn;
        scal_s[tid][1] = g;
        scal_s[tid][2] = e0 * inv;
        scal_s[tid][3] = e1 * inv;
        scal_s[tid][4] = e2 * inv;
        scal_s[tid][5] = 1.f + softplus_f(h[5]);
    }
    __syncthreads();

    // ---- phase 1: E = exp((beta/kn)*(1/mn)*(k . M_i)), prefetched ----
    {
        float cbs[4];
        #pragma unroll
        for (int reg = 0; reg < 4; reg++) cbs[reg] = scal_s[quad * 4 + reg][0];

        const bf16x8 af0 = *(const bf16x8*)&k_s[l16][quad * 8];
        const bf16x8 af1 = *(const bf16x8*)&k_s[l16][32 + quad * 8];
        const bf16x8 af2 = *(const bf16x8*)&k_s[l16][64 + quad * 8];
        const bf16x8 af3 = *(const bf16x8*)&k_s[l16][96 + quad * 8];

        const unsigned short* bp0 = Mb_sw + (size_t)(w * 16) * 2048 + lane * 8;
        bf16x8 f0 = *(const bf16x8*)(bp0);
        bf16x8 f1 = *(const bf16x8*)(bp0 + 512);
        bf16x8 f2 = *(const bf16x8*)(bp0 + 1024);
        bf16x8 f3 = *(const bf16x8*)(bp0 + 1536);
        float imc = imn[w * 256 + l16];

        float Sp[4] = {0.f, 0.f, 0.f, 0.f};
        #pragma unroll
        for (int t = 0; t < 16; t++) {
            const int nt = w * 16 + t;
            bf16x8 g0, g1, g2, g3;
            float imnext = 0.f;
            if (t < 15) {
                const unsigned short* bp = Mb_sw + (size_t)(nt + 1) * 2048 + lane * 8;
                g0 = *(const bf16x8*)(bp);
                g1 = *(const bf16x8*)(bp + 512);
                g2 = *(const bf16x8*)(bp + 1024);
                g3 = *(const bf16x8*)(bp + 1536);
                imnext = imn[(nt + 1) * 16 + l16];
            }
            f32x4 aA = {0.f, 0.f, 0.f, 0.f};
            f32x4 aB = {0.f, 0.f, 0.f, 0.f};
            aA = __builtin_amdgcn_mfma_f32_16x16x32_bf16(af0, f0, aA, 0, 0, 0);
            aB = __builtin_amdgcn_mfma_f32_16x16x32_bf16(af2, f2, aB, 0, 0, 0);
            aA = __builtin_amdgcn_mfma_f32_16x16x32_bf16(af1, f1, aA, 0, 0, 0);
            aB = __builtin_amdgcn_mfma_f32_16x16x32_bf16(af3, f3, aB, 0, 0, 0);
            const int n0 = nt * 16;
            #pragma unroll
            for (int reg = 0; reg < 4; reg++) {
                const float e = __expf((aA[reg] + aB[reg]) * cbs[reg] * imc);
                E_s[quad * 4 + reg][n0 + l16] = f2bf(e);
                Sp[reg] += e;
            }
            f0 = g0; f1 = g1; f2 = g2; f3 = g3; imc = imnext;
        }
        #pragma unroll
        for (int s = 1; s < 16; s <<= 1) {
            #pragma unroll
            for (int reg = 0; reg < 4; reg++) Sp[reg] += __shfl_xor(Sp[reg], s);
        }
        if (l16 == 0) {
            #pragma unroll
            for (int reg = 0; reg < 4; reg++) wred[quad * 4 + reg][w] = Sp[reg];
        }
    }
    __syncthreads();
    if (tid < 16) {
        float S = 0.f;
        #pragma unroll
        for (int i = 0; i < 8; i++) S += wred[tid][i];
        const float g = scal_s[tid][1];
        fa_s[tid] = g / S;
        fc_s[tid] = 1.f - g;
    }
    __syncthreads();

    // ---- phase 1.5: parallel shift+pow, in place, software-pipelined ----
    // Row r owned by a 32-lane half-wave; lane g owns chunks (g+32j)*8.
    // Prefetched chunk/edge reads of iter j+1 are never written during iter j
    // for g>0; g==0 left edge and g==31/j==7 right wrap go through carry/E0sav
    // registers, so early (stale) raw reads are discarded.
    {
        const int row  = tid >> 5;           // 0..15
        const int g    = tid & 31;
        const int base = tid & 32;           // wave-local half base
        const float s0 = scal_s[row][2], s1 = scal_s[row][3], s2 = scal_s[row][4];
        const float gmm = scal_s[row][5];
        const float fa = fa_s[row], fcm = fc_s[row];
        const float* wp = wprev + (size_t)(b0 + row) * NR;

        int c0 = g * 8;
        bf16x8 E8c = *(const bf16x8*)&E_s[row][c0];
        float eLc  = bf2f(E_s[row][(c0 + NR - 1) & (NR - 1)]);
        float eRc  = bf2f(E_s[row][c0 + 8]);
        float4 wac = *(const float4*)(wp + c0);
        float4 wbc = *(const float4*)(wp + c0 + 4);
        float wpLc = wp[(c0 + NR - 1) & (NR - 1)];
        float wpRc = wp[c0 + 8];

        float Zp = 0.f, carry = 0.f, E0sav = 0.f;
        #pragma unroll
        for (int j = 0; j < 8; j++) {
            bf16x8 E8n; float eLn = 0.f, eRn = 0.f, wpLn = 0.f, wpRn = 0.f;
            float4 wan, wbn;
            if (j < 7) {
                const int c1 = c0 + 256;
                E8n  = *(const bf16x8*)&E_s[row][c1];
                eLn  = bf2f(E_s[row][c1 - 1]);
                eRn  = bf2f(E_s[row][(c1 + 8) & (NR - 1)]);
                wan  = *(const float4*)(wp + c1);
                wbn  = *(const float4*)(wp + c1 + 4);
                wpLn = wp[c1 - 1];
                wpRn = wp[(c1 + 8) & (NR - 1)];
            }
            float ef[8];
            #pragma unroll
            for (int i = 0; i < 8; i++) ef[i] = bf2f((unsigned short)E8c[i]);
            if (j == 0) E0sav = __shfl(ef[0], base);
            const float eL = (g == 0 && j > 0) ? carry : eLc;
            const float eR = (g == 31 && j == 7) ? E0sav : eRc;
            carry = __shfl(ef[7], base + 31);

            float wg[10];
            wg[0] = fmaf(fa, eL,    fcm * wpLc);
            wg[1] = fmaf(fa, ef[0], fcm * wac.x);
            wg[2] = fmaf(fa, ef[1], fcm * wac.y);
            wg[3] = fmaf(fa, ef[2], fcm * wac.z);
            wg[4] = fmaf(fa, ef[3], fcm * wac.w);
            wg[5] = fmaf(fa, ef[4], fcm * wbc.x);
            wg[6] = fmaf(fa, ef[5], fcm * wbc.y);
            wg[7] = fmaf(fa, ef[6], fcm * wbc.z);
            wg[8] = fmaf(fa, ef[7], fcm * wbc.w);
            wg[9] = fmaf(fa, eR,    fcm * wpRc);

            bf16x8 out8;
            #pragma unroll
            for (int i = 0; i < 8; i++) {
                const float wt = fmaf(s0, wg[i], fmaf(s1, wg[i + 1], s2 * wg[i + 2])) + EPSF;
                const float pw = exp2f(gmm * log2f(wt));   // wt^gamma, wt > 0
                Zp += pw;
                out8[i] = (short)f2bf(pw);
            }
            *(bf16x8*)&E_s[row][c0] = out8;

            c0 += 256;
            E8c = E8n; eLc = eLn; eRc = eRn;
            wac = wan; wbc = wbn; wpLc = wpLn; wpRc = wpRn;
        }
        #pragma unroll
        for (int s = 1; s < 32; s <<= 1) Zp += __shfl_xor(Zp, s);
        if (g == 0) invZ_s[row] = 1.f / Zp;
    }
    __syncthreads();

    // ---- phase 2: r = (w_pow @ M) * invZ, prefetched Mt_sw frags ----
    {
        f32x4 acc0 = {0.f, 0.f, 0.f, 0.f};
        f32x4 acc1 = {0.f, 0.f, 0.f, 0.f};
        f32x4 acc2 = {0.f, 0.f, 0.f, 0.f};
        f32x4 acc3 = {0.f, 0.f, 0.f, 0.f};
        const unsigned short* bp = Mt_sw + (size_t)w * 32768 + lane * 8;
        bf16x8 c0v = *(const bf16x8*)(bp);
        bf16x8 c1v = *(const bf16x8*)(bp + 512);
        bf16x8 c2v = *(const bf16x8*)(bp + 1024);
        bf16x8 c3v = *(const bf16x8*)(bp + 1536);
        #pragma unroll
        for (int k0 = 0; k0 < NR; k0 += 128) {
            bf16x8 n0v, n1v, n2v, n3v;
            if (k0 < NR - 128) {
                const unsigned short* np = bp + (size_t)((k0 >> 5) + 4) * 512;
                n0v = *(const bf16x8*)(np);
                n1v = *(const bf16x8*)(np + 512);
                n2v = *(const bf16x8*)(np + 1024);
                n3v = *(const bf16x8*)(np + 1536);
            }
            const bf16x8 a0 = *(const bf16x8*)&E_s[l16][k0 + quad * 8];
            const bf16x8 a1 = *(const bf16x8*)&E_s[l16][k0 + 32 + quad * 8];
            const bf16x8 a2 = *(const bf16x8*)&E_s[l16][k0 + 64 + quad * 8];
            const bf16x8 a3 = *(const bf16x8*)&E_s[l16][k0 + 96 + quad * 8];
            acc0 = __builtin_amdgcn_mfma_f32_16x16x32_bf16(a0, c0v, acc0, 0, 0, 0);
            acc1 = __builtin_amdgcn_mfma_f32_16x16x32_bf16(a1, c1v, acc1, 0, 0, 0);
            acc2 = __builtin_amdgcn_mfma_f32_16x16x32_bf16(a2, c2v, acc2, 0, 0, 0);
            acc3 = __builtin_amdgcn_mfma_f32_16x16x32_bf16(a3, c3v, acc3, 0, 0, 0);
            c0v = n0v; c1v = n1v; c2v = n2v; c3v = n3v;
        }
        #pragma unroll
        for (int reg = 0; reg < 4; reg++) {
            const int m = quad * 4 + reg;
            const float v = (acc0[reg] + acc1[reg]) + (acc2[reg] + acc3[reg]);
            out[(size_t)(b0 + m) * NC + w * 16 + l16] = v * invZ_s[m];
        }
    }
}

extern "C" void kernel_launch(void* const* d_in, const int* in_sizes, int n_in,
                              void* d_out, int out_size, void* d_ws, size_t ws_size,
                              hipStream_t stream) {
    const float* x     = (const float*)d_in[0];
    const float* Wfc   = (const float*)d_in[1];
    const float* bfc   = (const float*)d_in[2];
    const float* M     = (const float*)d_in[3];
    const float* wprev = (const float*)d_in[4];
    float* out = (float*)d_out;

    char* ws = (char*)d_ws;
    float*          imn   = (float*)(ws);                      // 8192 B
    unsigned short* Mb_sw = (unsigned short*)(ws + 8192);      // 524288 B
    unsigned short* Mt_sw = (unsigned short*)(ws + 532480);    // 524288 B
    unsigned short* Wt_sw = (unsigned short*)(ws + 1056768);   // 294912 B

    hipLaunchKernelGGL(prep_all, dim3(NR + KCTRL), dim3(64), 0, stream,
                       M, Mb_sw, Mt_sw, imn, Wfc, Wt_sw);
    hipLaunchKernelGGL(fused_ntm, dim3(NB / 16), dim3(512), 0, stream,
                       x, Wt_sw, bfc, Mb_sw, Mt_sw, imn, wprev, out);
}